// Round 2
// baseline (26358.627 us; speedup 1.0000x reference)
//
#include <hip/hip_runtime.h>
#include <math.h>

// TGN AttentionEmbedding — round 1: correct-first f32 baseline, defensive
// restructure of the online-softmax core (single-writer state, LDS O-accum,
// explicit barriers, no intra-wave lockstep assumptions, no inf arithmetic).

#define NT   256
#define TM   8
#define KNB  10
#define DIM  128
#define TDIM 128
#define QDIM 256
#define KDIM 384
#define KVPAD 4      // keyv row stride 388 floats (16B-aligned rows)

__global__ __launch_bounds__(NT) void tga_kernel(
    const float* __restrict__ node_feat,
    const float* __restrict__ memory_,
    const float* __restrict__ edge_feat,
    const float* __restrict__ time_w,
    const float* __restrict__ time_b,
    const float* __restrict__ Wq, const float* __restrict__ bq,
    const float* __restrict__ Wk, const float* __restrict__ bk,
    const float* __restrict__ Wv, const float* __restrict__ bv,
    const float* __restrict__ Wo, const float* __restrict__ bo,
    const float* __restrict__ W1, const float* __restrict__ b1,
    const float* __restrict__ W2, const float* __restrict__ b2,
    const float* __restrict__ timestamps,
    const int*   __restrict__ src_idx,     // mode 0: node ids [M]
    const float* __restrict__ src_dense,   // mode 1: [M,128]
    const int*   __restrict__ nbr_idx,     // [M,K] (mask source always)
    const float* __restrict__ nbr_dense,   // mode 1: [M*K,128]
    const int*   __restrict__ edge_idx,    // [M,K]
    const float* __restrict__ edge_times,  // [M,K]
    int ts_div, int mode,
    float* __restrict__ out)               // [M,128]
{
    __shared__ __align__(16) float s_src[TM][DIM];
    __shared__ __align__(16) float s_stime[TDIM];
    __shared__ __align__(16) float s_q[TM][QDIM];
    __shared__ __align__(16) float s_keyv[TM][KDIM + KVPAD]; // later: att out (cols 0..255)
    __shared__ __align__(16) float s_k[TM][QDIM];            // later: Wo output
    __shared__ __align__(16) float s_v[TM][QDIM];            // later: h1 (cols 0..127)
    __shared__ __align__(16) float s_o[TM][QDIM];            // online O accumulator
    __shared__ float s_m[TM][2];
    __shared__ float s_l[TM][2];
    __shared__ float s_alpha[TM][2];
    __shared__ float s_p[TM][2];
    __shared__ int   s_nbr[TM][KNB];
    __shared__ int   s_edge[TM][KNB];
    __shared__ float s_dt[TM][KNB];
    __shared__ int   s_inv[TM];

    const int tid  = threadIdx.x;
    const int row0 = blockIdx.x * TM;
    const int r8   = tid >> 5;        // row staged by this half-wave in gather
    const int lane = tid & 31;

    // ---- stage 1: inits + indices + dt + src features + src time encoding
    if (tid < TM * 2) {
        s_m[tid >> 1][tid & 1] = -1e30f;
        s_l[tid >> 1][tid & 1] = 0.f;
    }
    for (int idx = tid; idx < TM * QDIM; idx += NT)
        s_o[idx >> 8][idx & 255] = 0.f;
    if (tid < TM * KNB) {
        int r = tid / KNB, j = tid - r * KNB;
        int grow = row0 + r;
        s_nbr[r][j]  = nbr_idx[grow * KNB + j];
        s_edge[r][j] = edge_idx[grow * KNB + j];
        float ts = timestamps[grow / ts_div];
        s_dt[r][j] = ts - edge_times[grow * KNB + j];
    }
    if (tid < TDIM) s_stime[tid] = cosf(time_b[tid]);  // tenc(0) = cos(b)
    for (int idx = tid; idx < TM * DIM; idx += NT) {
        int r = idx >> 7, i = idx & 127;
        float v;
        if (mode == 0) {
            int s = src_idx[row0 + r];
            v = node_feat[(size_t)s * DIM + i] + memory_[(size_t)s * DIM + i];
        } else {
            v = src_dense[(size_t)(row0 + r) * DIM + i];
        }
        s_src[r][i] = v;
    }
    __syncthreads();

    if (tid < TM) {
        bool inv = true;
        for (int j = 0; j < KNB; j++) inv = inv && (s_nbr[tid][j] == 0);
        s_inv[tid] = inv ? 1 : 0;
    }

    // ---- stage 2: q projection. thread = output col; query = [src || stime]
    {
        const float* wq = Wq + (size_t)tid * QDIM;
        float acc[TM];
#pragma unroll
        for (int r = 0; r < TM; r++) acc[r] = 0.f;
        float tdot = 0.f;
        for (int i = 0; i < TDIM; i += 4) {          // time part: same for all rows
            float4 w = *(const float4*)(wq + DIM + i);
            float4 x = *(const float4*)(&s_stime[i]);
            tdot += w.x*x.x + w.y*x.y + w.z*x.z + w.w*x.w;
        }
        for (int i = 0; i < DIM; i += 4) {
            float4 w = *(const float4*)(wq + i);
#pragma unroll
            for (int r = 0; r < TM; r++) {
                float4 x = *(const float4*)(&s_src[r][i]);
                acc[r] += w.x*x.x + w.y*x.y + w.z*x.z + w.w*x.w;
            }
        }
        float bias = tdot + bq[tid];
#pragma unroll
        for (int r = 0; r < TM; r++) s_q[r][tid] = acc[r] + bias;
    }
    __syncthreads();   // s_q visible before first score; s_inv visible

    // ---- stage 3: neighbor loop with online softmax (single-writer state)
    for (int j = 0; j < KNB; j++) {
        // (a) build keyv[r8][384] = [neigh_emb || edge_feat || tenc(dt)]
        {
            int   n  = s_nbr[r8][j];
            int   e  = s_edge[r8][j];
            float dt = s_dt[r8][j];
            for (int seg = 0; seg < 12; seg++) {
                int i = lane + 32 * seg;
                float v;
                if (i < DIM) {
                    if (mode == 0)
                        v = node_feat[(size_t)n * DIM + i] + memory_[(size_t)n * DIM + i];
                    else
                        v = nbr_dense[((size_t)(row0 + r8) * KNB + j) * DIM + i];
                } else if (i < 2 * DIM) {
                    v = edge_feat[(size_t)e * DIM + (i - DIM)];
                } else {
                    int ti = i - 2 * DIM;
                    v = cosf(dt * time_w[ti] + time_b[ti]);
                }
                s_keyv[r8][i] = v;
            }
        }
        __syncthreads();
        // (b) k,v projection: thread = out col, 8 rows each; shared keyv broadcast
        {
            const float* wk = Wk + (size_t)tid * KDIM;
            const float* wv = Wv + (size_t)tid * KDIM;
            float ak[TM], av[TM];
#pragma unroll
            for (int r = 0; r < TM; r++) { ak[r] = 0.f; av[r] = 0.f; }
            for (int i = 0; i < KDIM; i += 4) {
                float4 wk4 = *(const float4*)(wk + i);
                float4 wv4 = *(const float4*)(wv + i);
#pragma unroll
                for (int r = 0; r < TM; r++) {
                    float4 x = *(const float4*)(&s_keyv[r][i]);
                    ak[r] += wk4.x*x.x + wk4.y*x.y + wk4.z*x.z + wk4.w*x.w;
                    av[r] += wv4.x*x.x + wv4.y*x.y + wv4.z*x.z + wv4.w*x.w;
                }
            }
            float bkt = bk[tid], bvt = bv[tid];
#pragma unroll
            for (int r = 0; r < TM; r++) {
                s_k[r][tid] = ak[r] + bkt;
                s_v[r][tid] = av[r] + bvt;
            }
        }
        __syncthreads();
        // (c) score + full online-state update, one thread per (row, head)
        if (tid < TM * 2) {
            int r = tid >> 1, h = tid & 1;
            const float* qp = &s_q[r][h * 128];
            const float* kp = &s_k[r][h * 128];
            float sc = 0.f;
            for (int i = 0; i < 128; i++) sc += qp[i] * kp[i];
            sc *= 0.08838834764831845f;   // 1/sqrt(128)
            bool masked = (s_nbr[r][j] == 0) && !(s_inv[r] && j == 0);
            if (masked) sc = -1e9f;
            float mo = s_m[r][h];
            float mn = fmaxf(mo, sc);
            float alpha = expf(mo - mn);  // exactly 0 wipes pre-real masked prefix
            float p     = expf(sc - mn);
            s_m[r][h]     = mn;
            s_l[r][h]     = s_l[r][h] * alpha + p;
            s_alpha[r][h] = alpha;
            s_p[r][h]     = p;
        }
        __syncthreads();
        // (d) O-accumulator update in LDS: thread = col, all 8 rows
        {
            int h = tid >> 7;
            float al[2] = { 0.f, 0.f }; // avoid re-reading per row
            float pp[2];
            al[0] = 0.f; // placeholder; real reads below
            (void)al; (void)pp;
#pragma unroll
            for (int r = 0; r < TM; r++) {
                float a = s_alpha[r][h];
                float p = s_p[r][h];
                s_o[r][tid] = s_o[r][tid] * a + p * s_v[r][tid];
            }
        }
        __syncthreads();
    }

    // ---- stage 4: normalize attention output -> s_keyv cols 0..255
    {
        int h = tid >> 7;
#pragma unroll
        for (int r = 0; r < TM; r++)
            s_keyv[r][tid] = s_o[r][tid] / s_l[r][h];
    }
    __syncthreads();

    // ---- stage 5: Wo projection + invalid zeroing -> s_k
    {
        const float* wo = Wo + (size_t)tid * QDIM;
        float acc[TM];
#pragma unroll
        for (int r = 0; r < TM; r++) acc[r] = 0.f;
        for (int i = 0; i < QDIM; i += 4) {
            float4 w = *(const float4*)(wo + i);
#pragma unroll
            for (int r = 0; r < TM; r++) {
                float4 x = *(const float4*)(&s_keyv[r][i]);
                acc[r] += w.x*x.x + w.y*x.y + w.z*x.z + w.w*x.w;
            }
        }
        float bot = bo[tid];
#pragma unroll
        for (int r = 0; r < TM; r++)
            s_k[r][tid] = s_inv[r] ? 0.f : (acc[r] + bot);
    }
    __syncthreads();

    // ---- stage 6: FFN layer 1: h = relu([out || src] @ W1.T + b1) -> s_v[.][0..127]
    {
        int c = tid & 127;
        int rbase = (tid >> 7) * 4;
        const float* w1 = W1 + (size_t)c * (QDIM + DIM);
        float acc[4] = {0.f, 0.f, 0.f, 0.f};
        for (int i = 0; i < QDIM; i += 4) {
            float4 w = *(const float4*)(w1 + i);
#pragma unroll
            for (int rr = 0; rr < 4; rr++) {
                float4 x = *(const float4*)(&s_k[rbase + rr][i]);
                acc[rr] += w.x*x.x + w.y*x.y + w.z*x.z + w.w*x.w;
            }
        }
        for (int i = 0; i < DIM; i += 4) {
            float4 w = *(const float4*)(w1 + QDIM + i);
#pragma unroll
            for (int rr = 0; rr < 4; rr++) {
                float4 x = *(const float4*)(&s_src[rbase + rr][i]);
                acc[rr] += w.x*x.x + w.y*x.y + w.z*x.z + w.w*x.w;
            }
        }
        float b1c = b1[c];
#pragma unroll
        for (int rr = 0; rr < 4; rr++)
            s_v[rbase + rr][c] = fmaxf(acc[rr] + b1c, 0.f);
    }
    __syncthreads();

    // ---- stage 7: FFN layer 2 -> global
    {
        int c = tid & 127;
        int rbase = (tid >> 7) * 4;
        const float* w2 = W2 + (size_t)c * DIM;
        float acc[4] = {0.f, 0.f, 0.f, 0.f};
        for (int i = 0; i < DIM; i += 4) {
            float4 w = *(const float4*)(w2 + i);
#pragma unroll
            for (int rr = 0; rr < 4; rr++) {
                float4 x = *(const float4*)(&s_v[rbase + rr][i]);
                acc[rr] += w.x*x.x + w.y*x.y + w.z*x.z + w.w*x.w;
            }
        }
        float b2c = b2[c];
#pragma unroll
        for (int rr = 0; rr < 4; rr++)
            out[(size_t)(row0 + rbase + rr) * DIM + c] = acc[rr] + b2c;
    }
}

extern "C" void kernel_launch(void* const* d_in, const int* in_sizes, int n_in,
                              void* d_out, int out_size, void* d_ws, size_t ws_size,
                              hipStream_t stream) {
    const float* node_feat = (const float*)d_in[0];
    const float* memory_   = (const float*)d_in[1];
    const float* edge_feat = (const float*)d_in[2];
    const float* time_w    = (const float*)d_in[3];
    const float* time_b    = (const float*)d_in[4];
    const float* Wq = (const float*)d_in[5];
    const float* bq = (const float*)d_in[6];
    const float* Wk = (const float*)d_in[7];
    const float* bk = (const float*)d_in[8];
    const float* Wv = (const float*)d_in[9];
    const float* bv = (const float*)d_in[10];
    const float* Wo = (const float*)d_in[11];
    const float* bo = (const float*)d_in[12];
    const float* W1 = (const float*)d_in[13];
    const float* b1 = (const float*)d_in[14];
    const float* W2 = (const float*)d_in[15];
    const float* b2 = (const float*)d_in[16];
    const float* timestamps  = (const float*)d_in[17];
    const int*   src_nodes   = (const int*)d_in[18];
    const int*   neighbors1  = (const int*)d_in[19];
    const int*   edge_idx1   = (const int*)d_in[20];
    const float* edge_times1 = (const float*)d_in[21];
    const int*   neighbors2  = (const int*)d_in[22];
    const int*   edge_idx2   = (const int*)d_in[23];
    const float* edge_times2 = (const float*)d_in[24];

    const int B = 8192, K = KNB;
    float* src_l1   = (float*)d_ws;                    // [8192,128]  = 4 MB
    float* neigh_l1 = src_l1 + (size_t)B * DIM;        // [81920,128] = 40 MB

    const int QQ = QDIM * QDIM, QK = QDIM * KDIM, DC = DIM * (QDIM + DIM), DD = DIM * DIM;

    // layer-1 embedding of flattened first-hop neighbors (M = B*K)
    tga_kernel<<<(B * K) / TM, NT, 0, stream>>>(
        node_feat, memory_, edge_feat, time_w, time_b,
        Wq, bq, Wk, bk, Wv, bv, Wo, bo, W1, b1, W2, b2, timestamps,
        neighbors1, nullptr, neighbors2, nullptr, edge_idx2, edge_times2,
        K, 0, neigh_l1);

    // layer-1 embedding of src nodes (M = B)
    tga_kernel<<<B / TM, NT, 0, stream>>>(
        node_feat, memory_, edge_feat, time_w, time_b,
        Wq, bq, Wk, bk, Wv, bv, Wo, bo, W1, b1, W2, b2, timestamps,
        src_nodes, nullptr, neighbors1, nullptr, edge_idx1, edge_times1,
        1, 0, src_l1);

    // layer-2 aggregation (M = B, params index 1, dense inputs from ws)
    tga_kernel<<<B / TM, NT, 0, stream>>>(
        node_feat, memory_, edge_feat, time_w, time_b,
        Wq + QQ, bq + QDIM, Wk + QK, bk + QDIM, Wv + QK, bv + QDIM,
        Wo + QQ, bo + QDIM, W1 + DC, b1 + DIM, W2 + DD, b2 + DIM, timestamps,
        nullptr, src_l1, neighbors1, neigh_l1, edge_idx1, edge_times1,
        1, 1, (float*)d_out);
}

// Round 3
// 4617.905 us; speedup vs baseline: 5.7079x; 5.7079x over previous
//
#include <hip/hip_runtime.h>
#include <math.h>

// TGN AttentionEmbedding — round 2: algebraic restructure.
//   score[r,j,h] = qk[r,h,:384] . keyv[r,j,:384] + q.bk      (qk = Wk_h^T q_h)
//   out[r,h]     = Wv_h @ (sum_j attn_j keyv[r,j]) + bv_h    (attn sums to 1)
// 5.3x FLOP cut vs direct K/V projection; neighbor loop is register-resident
// (half-wave per row, 3x float4 per lane), barrier-free, online softmax.

#define NT   256
#define TM   8
#define KNB  10
#define DIM  128
#define TDIM 128
#define QDIM 256
#define KDIM 384
#define QKS  (KDIM + 4)   // 388 floats: [r][h] row base = 1552 B, 16B-aligned

__global__ __launch_bounds__(NT) void tga_kernel(
    const float* __restrict__ node_feat,
    const float* __restrict__ memory_,
    const float* __restrict__ edge_feat,
    const float* __restrict__ time_w,
    const float* __restrict__ time_b,
    const float* __restrict__ Wq, const float* __restrict__ bq,
    const float* __restrict__ Wk, const float* __restrict__ bk,
    const float* __restrict__ Wv, const float* __restrict__ bv,
    const float* __restrict__ Wo, const float* __restrict__ bo,
    const float* __restrict__ W1, const float* __restrict__ b1,
    const float* __restrict__ W2, const float* __restrict__ b2,
    const float* __restrict__ timestamps,
    const int*   __restrict__ src_idx,     // mode 0: node ids [M]
    const float* __restrict__ src_dense,   // mode 1: [M,128]
    const int*   __restrict__ nbr_idx,     // [M,K] (mask source always)
    const float* __restrict__ nbr_dense,   // mode 1: [M*K,128]
    const int*   __restrict__ edge_idx,    // [M,K]
    const float* __restrict__ edge_times,  // [M,K]
    int ts_div, int mode,
    float* __restrict__ out)               // [M,128]
{
    __shared__ __align__(16) float s_src[TM][DIM];
    __shared__ __align__(16) float s_stime[TDIM];
    __shared__ __align__(16) float s_q[TM][QDIM];      // q; later: att (pre-Wo)
    __shared__ __align__(16) float s_qkmix[TM][2][QKS];// qk; later: mixed; later: h1
    __shared__ __align__(16) float s_wo[TM][QDIM];     // Wo output
    __shared__ float s_qbk[TM][2];
    __shared__ int   s_nbr[TM][KNB];
    __shared__ int   s_edge[TM][KNB];
    __shared__ float s_dt[TM][KNB];
    __shared__ int   s_inv[TM];

    const int tid  = threadIdx.x;
    const int row0 = blockIdx.x * TM;
    const int r8   = tid >> 5;        // half-wave's row in the neighbor loop
    const int l32  = tid & 31;

    // ---- stage 1: indices, dt, src features, src time encoding
    if (tid < TM * KNB) {
        int r = tid / KNB, j = tid - r * KNB;
        int grow = row0 + r;
        s_nbr[r][j]  = nbr_idx[grow * KNB + j];
        s_edge[r][j] = edge_idx[grow * KNB + j];
        float ts = timestamps[grow / ts_div];
        s_dt[r][j] = ts - edge_times[grow * KNB + j];
    }
    if (tid < TDIM) s_stime[tid] = cosf(time_b[tid]);  // tenc(0) = cos(b)
    for (int idx = tid; idx < TM * DIM; idx += NT) {
        int r = idx >> 7, i = idx & 127;
        float v;
        if (mode == 0) {
            int s = src_idx[row0 + r];
            v = node_feat[(size_t)s * DIM + i] + memory_[(size_t)s * DIM + i];
        } else {
            v = src_dense[(size_t)(row0 + r) * DIM + i];
        }
        s_src[r][i] = v;
    }
    __syncthreads();

    if (tid < TM) {
        bool inv = true;
        for (int j = 0; j < KNB; j++) inv = inv && (s_nbr[tid][j] == 0);
        s_inv[tid] = inv ? 1 : 0;
    }

    // ---- stage 2: q projection. thread = output col; query = [src || stime]
    {
        const float* wq = Wq + (size_t)tid * QDIM;
        float acc[TM];
#pragma unroll
        for (int r = 0; r < TM; r++) acc[r] = 0.f;
        float tdot = 0.f;
        for (int i = 0; i < TDIM; i += 4) {          // time part: same for all rows
            float4 w = *(const float4*)(wq + DIM + i);
            float4 x = *(const float4*)(&s_stime[i]);
            tdot += w.x*x.x + w.y*x.y + w.z*x.z + w.w*x.w;
        }
        for (int i = 0; i < DIM; i += 4) {
            float4 w = *(const float4*)(wq + i);
#pragma unroll
            for (int r = 0; r < TM; r++) {
                float4 x = *(const float4*)(&s_src[r][i]);
                acc[r] += w.x*x.x + w.y*x.y + w.z*x.z + w.w*x.w;
            }
        }
        float bias = tdot + bq[tid];
#pragma unroll
        for (int r = 0; r < TM; r++) s_q[r][tid] = acc[r] + bias;
    }
    __syncthreads();   // q + s_inv visible

    // ---- stage 2b: qbk[r][h] = q_h . bk_h  (16 threads, tiny)
    if (tid < TM * 2) {
        int r = tid >> 1, h = tid & 1;
        const float* qp = &s_q[r][h * 128];
        const float* bp = bk + h * 128;
        float s = 0.f;
        for (int i = 0; i < 128; i++) s += qp[i] * bp[i];
        s_qbk[r][h] = s;
    }

    // ---- stage 3: qk[r][h][i] = sum_c q[r][h*128+c] * Wk[h*128+c][i]
    {
        int h = tid >> 7, i0 = tid & 127;
        const float* wkh = Wk + (size_t)h * 128 * KDIM + i0;
        float acc[TM][3];
#pragma unroll
        for (int r = 0; r < TM; r++)
            for (int b = 0; b < 3; b++) acc[r][b] = 0.f;
        for (int c4 = 0; c4 < 128; c4 += 4) {
            float4 q4[TM];
#pragma unroll
            for (int r = 0; r < TM; r++)
                q4[r] = *(const float4*)(&s_q[r][h * 128 + c4]);
#pragma unroll
            for (int cc = 0; cc < 4; cc++) {
                const float* wr = wkh + (size_t)(c4 + cc) * KDIM;
                float w0 = wr[0], w1 = wr[128], w2 = wr[256];
#pragma unroll
                for (int r = 0; r < TM; r++) {
                    float qc = (cc == 0) ? q4[r].x : (cc == 1) ? q4[r].y
                             : (cc == 2) ? q4[r].z : q4[r].w;
                    acc[r][0] += qc * w0;
                    acc[r][1] += qc * w1;
                    acc[r][2] += qc * w2;
                }
            }
        }
#pragma unroll
        for (int r = 0; r < TM; r++)
            for (int b = 0; b < 3; b++)
                s_qkmix[r][h][i0 + 128 * b] = acc[r][b];
    }
    __syncthreads();

    // ---- stage 4: neighbor loop — register-resident, barrier-free
    float4 qk0[3], qk1[3], mix0[3], mix1[3];
#pragma unroll
    for (int b = 0; b < 3; b++) {
        qk0[b] = *(const float4*)(&s_qkmix[r8][0][4 * l32 + 128 * b]);
        qk1[b] = *(const float4*)(&s_qkmix[r8][1][4 * l32 + 128 * b]);
        mix0[b] = make_float4(0.f, 0.f, 0.f, 0.f);
        mix1[b] = make_float4(0.f, 0.f, 0.f, 0.f);
    }
    float4 twv = *(const float4*)(time_w + 4 * l32);
    float4 tbv = *(const float4*)(time_b + 4 * l32);
    const float qbk0 = s_qbk[r8][0], qbk1 = s_qbk[r8][1];
    const int   invr = s_inv[r8];
    float m0 = -1e30f, l0 = 0.f, m1 = -1e30f, l1 = 0.f;

    for (int j = 0; j < KNB; j++) {
        int   n  = s_nbr[r8][j];
        int   e  = s_edge[r8][j];
        float dt = s_dt[r8][j];
        float4 kv0, kv1, kv2;
        if (mode == 0) {
            float4 a = *(const float4*)(node_feat + (size_t)n * DIM + 4 * l32);
            float4 b = *(const float4*)(memory_   + (size_t)n * DIM + 4 * l32);
            kv0 = make_float4(a.x + b.x, a.y + b.y, a.z + b.z, a.w + b.w);
        } else {
            kv0 = *(const float4*)(nbr_dense +
                    ((size_t)(row0 + r8) * KNB + j) * DIM + 4 * l32);
        }
        kv1 = *(const float4*)(edge_feat + (size_t)e * DIM + 4 * l32);
        kv2.x = cosf(dt * twv.x + tbv.x);
        kv2.y = cosf(dt * twv.y + tbv.y);
        kv2.z = cosf(dt * twv.z + tbv.z);
        kv2.w = cosf(dt * twv.w + tbv.w);

        float s0 = kv0.x*qk0[0].x + kv0.y*qk0[0].y + kv0.z*qk0[0].z + kv0.w*qk0[0].w
                 + kv1.x*qk0[1].x + kv1.y*qk0[1].y + kv1.z*qk0[1].z + kv1.w*qk0[1].w
                 + kv2.x*qk0[2].x + kv2.y*qk0[2].y + kv2.z*qk0[2].z + kv2.w*qk0[2].w;
        float s1 = kv0.x*qk1[0].x + kv0.y*qk1[0].y + kv0.z*qk1[0].z + kv0.w*qk1[0].w
                 + kv1.x*qk1[1].x + kv1.y*qk1[1].y + kv1.z*qk1[1].z + kv1.w*qk1[1].w
                 + kv2.x*qk1[2].x + kv2.y*qk1[2].y + kv2.z*qk1[2].z + kv2.w*qk1[2].w;
        s0 += __shfl_xor(s0, 1, 32);  s1 += __shfl_xor(s1, 1, 32);
        s0 += __shfl_xor(s0, 2, 32);  s1 += __shfl_xor(s1, 2, 32);
        s0 += __shfl_xor(s0, 4, 32);  s1 += __shfl_xor(s1, 4, 32);
        s0 += __shfl_xor(s0, 8, 32);  s1 += __shfl_xor(s1, 8, 32);
        s0 += __shfl_xor(s0, 16, 32); s1 += __shfl_xor(s1, 16, 32);
        s0 = (s0 + qbk0) * 0.08838834764831845f;
        s1 = (s1 + qbk1) * 0.08838834764831845f;
        bool masked = (n == 0) && !(invr && j == 0);
        if (masked) { s0 = -1e9f; s1 = -1e9f; }

        float mn0 = fmaxf(m0, s0);
        float a0  = expf(m0 - mn0);   // exact 0 wipes masked prefix
        float p0  = expf(s0 - mn0);
        l0 = l0 * a0 + p0; m0 = mn0;
        float mn1 = fmaxf(m1, s1);
        float a1  = expf(m1 - mn1);
        float p1  = expf(s1 - mn1);
        l1 = l1 * a1 + p1; m1 = mn1;

#define MIXUP(mx, aa, pp, kv) \
        mx.x = mx.x * aa + pp * kv.x; mx.y = mx.y * aa + pp * kv.y; \
        mx.z = mx.z * aa + pp * kv.z; mx.w = mx.w * aa + pp * kv.w;
        MIXUP(mix0[0], a0, p0, kv0) MIXUP(mix0[1], a0, p0, kv1) MIXUP(mix0[2], a0, p0, kv2)
        MIXUP(mix1[0], a1, p1, kv0) MIXUP(mix1[1], a1, p1, kv1) MIXUP(mix1[2], a1, p1, kv2)
#undef MIXUP
    }
    {
        float il0 = 1.f / l0, il1 = 1.f / l1;
#pragma unroll
        for (int b = 0; b < 3; b++) {
            float4 w0 = make_float4(mix0[b].x*il0, mix0[b].y*il0, mix0[b].z*il0, mix0[b].w*il0);
            float4 w1 = make_float4(mix1[b].x*il1, mix1[b].y*il1, mix1[b].z*il1, mix1[b].w*il1);
            *(float4*)(&s_qkmix[r8][0][4 * l32 + 128 * b]) = w0;  // own slots only
            *(float4*)(&s_qkmix[r8][1][4 * l32 + 128 * b]) = w1;
        }
    }
    __syncthreads();

    // ---- stage 5: att[r][tid] = Wv[tid,:] . mixed[r][h] + bv  -> s_q
    {
        int h = tid >> 7;
        const float* wv = Wv + (size_t)tid * KDIM;
        float acc[TM];
#pragma unroll
        for (int r = 0; r < TM; r++) acc[r] = 0.f;
        for (int i = 0; i < KDIM; i += 4) {
            float4 w = *(const float4*)(wv + i);
#pragma unroll
            for (int r = 0; r < TM; r++) {
                float4 x = *(const float4*)(&s_qkmix[r][h][i]);
                acc[r] += w.x*x.x + w.y*x.y + w.z*x.z + w.w*x.w;
            }
        }
        float bvt = bv[tid];
#pragma unroll
        for (int r = 0; r < TM; r++) s_q[r][tid] = acc[r] + bvt;
    }
    __syncthreads();

    // ---- stage 6: Wo projection + invalid zeroing -> s_wo
    {
        const float* wo = Wo + (size_t)tid * QDIM;
        float acc[TM];
#pragma unroll
        for (int r = 0; r < TM; r++) acc[r] = 0.f;
        for (int i = 0; i < QDIM; i += 4) {
            float4 w = *(const float4*)(wo + i);
#pragma unroll
            for (int r = 0; r < TM; r++) {
                float4 x = *(const float4*)(&s_q[r][i]);
                acc[r] += w.x*x.x + w.y*x.y + w.z*x.z + w.w*x.w;
            }
        }
        float bot = bo[tid];
#pragma unroll
        for (int r = 0; r < TM; r++)
            s_wo[r][tid] = s_inv[r] ? 0.f : (acc[r] + bot);
    }
    __syncthreads();

    // ---- stage 7: FFN1: h1 = relu([wo || src] @ W1.T + b1) -> s_qkmix[r][0][c]
    {
        int c = tid & 127;
        int rbase = (tid >> 7) * 4;
        const float* w1 = W1 + (size_t)c * (QDIM + DIM);
        float acc[4] = {0.f, 0.f, 0.f, 0.f};
        for (int i = 0; i < QDIM; i += 4) {
            float4 w = *(const float4*)(w1 + i);
#pragma unroll
            for (int rr = 0; rr < 4; rr++) {
                float4 x = *(const float4*)(&s_wo[rbase + rr][i]);
                acc[rr] += w.x*x.x + w.y*x.y + w.z*x.z + w.w*x.w;
            }
        }
        for (int i = 0; i < DIM; i += 4) {
            float4 w = *(const float4*)(w1 + QDIM + i);
#pragma unroll
            for (int rr = 0; rr < 4; rr++) {
                float4 x = *(const float4*)(&s_src[rbase + rr][i]);
                acc[rr] += w.x*x.x + w.y*x.y + w.z*x.z + w.w*x.w;
            }
        }
        float b1c = b1[c];
#pragma unroll
        for (int rr = 0; rr < 4; rr++)
            s_qkmix[rbase + rr][0][c] = fmaxf(acc[rr] + b1c, 0.f);
    }
    __syncthreads();

    // ---- stage 8: FFN2 -> global
    {
        int c = tid & 127;
        int rbase = (tid >> 7) * 4;
        const float* w2 = W2 + (size_t)c * DIM;
        float acc[4] = {0.f, 0.f, 0.f, 0.f};
        for (int i = 0; i < DIM; i += 4) {
            float4 w = *(const float4*)(w2 + i);
#pragma unroll
            for (int rr = 0; rr < 4; rr++) {
                float4 x = *(const float4*)(&s_qkmix[rbase + rr][0][i]);
                acc[rr] += w.x*x.x + w.y*x.y + w.z*x.z + w.w*x.w;
            }
        }
        float b2c = b2[c];
#pragma unroll
        for (int rr = 0; rr < 4; rr++)
            out[(size_t)(row0 + rbase + rr) * DIM + c] = acc[rr] + b2c;
    }
}

extern "C" void kernel_launch(void* const* d_in, const int* in_sizes, int n_in,
                              void* d_out, int out_size, void* d_ws, size_t ws_size,
                              hipStream_t stream) {
    const float* node_feat = (const float*)d_in[0];
    const float* memory_   = (const float*)d_in[1];
    const float* edge_feat = (const float*)d_in[2];
    const float* time_w    = (const float*)d_in[3];
    const float* time_b    = (const float*)d_in[4];
    const float* Wq = (const float*)d_in[5];
    const float* bq = (const float*)d_in[6];
    const float* Wk = (const float*)d_in[7];
    const float* bk = (const float*)d_in[8];
    const float* Wv = (const float*)d_in[9];
    const float* bv = (const float*)d_in[10];
    const float* Wo = (const float*)d_in[11];
    const float* bo = (const float*)d_in[12];
    const float* W1 = (const float*)d_in[13];
    const float* b1 = (const float*)d_in[14];
    const float* W2 = (const float*)d_in[15];
    const float* b2 = (const float*)d_in[16];
    const float* timestamps  = (const float*)d_in[17];
    const int*   src_nodes   = (const int*)d_in[18];
    const int*   neighbors1  = (const int*)d_in[19];
    const int*   edge_idx1   = (const int*)d_in[20];
    const float* edge_times1 = (const float*)d_in[21];
    const int*   neighbors2  = (const int*)d_in[22];
    const int*   edge_idx2   = (const int*)d_in[23];
    const float* edge_times2 = (const float*)d_in[24];

    const int B = 8192, K = KNB;
    float* src_l1   = (float*)d_ws;                    // [8192,128]  = 4 MB
    float* neigh_l1 = src_l1 + (size_t)B * DIM;        // [81920,128] = 40 MB

    const int QQ = QDIM * QDIM, QK = QDIM * KDIM, DC = DIM * (QDIM + DIM), DD = DIM * DIM;

    // layer-1 embedding of flattened first-hop neighbors (M = B*K)
    tga_kernel<<<(B * K) / TM, NT, 0, stream>>>(
        node_feat, memory_, edge_feat, time_w, time_b,
        Wq, bq, Wk, bk, Wv, bv, Wo, bo, W1, b1, W2, b2, timestamps,
        neighbors1, nullptr, neighbors2, nullptr, edge_idx2, edge_times2,
        K, 0, neigh_l1);

    // layer-1 embedding of src nodes (M = B)
    tga_kernel<<<B / TM, NT, 0, stream>>>(
        node_feat, memory_, edge_feat, time_w, time_b,
        Wq, bq, Wk, bk, Wv, bv, Wo, bo, W1, b1, W2, b2, timestamps,
        src_nodes, nullptr, neighbors1, nullptr, edge_idx1, edge_times1,
        1, 0, src_l1);

    // layer-2 aggregation (M = B, params index 1, dense inputs from ws)
    tga_kernel<<<B / TM, NT, 0, stream>>>(
        node_feat, memory_, edge_feat, time_w, time_b,
        Wq + QQ, bq + QDIM, Wk + QK, bk + QDIM, Wv + QK, bv + QDIM,
        Wo + QQ, bo + QDIM, W1 + DC, b1 + DIM, W2 + DD, b2 + DIM, timestamps,
        nullptr, src_l1, neighbors1, neigh_l1, edge_idx1, edge_times1,
        1, 1, (float*)d_out);
}